// Round 1
// baseline (546.925 us; speedup 1.0000x reference)
//
#include <hip/hip_runtime.h>
#include <hip/hip_bf16.h>
#include <math.h>

#define B_ 64
#define P_ 2048
#define E_ 512
#define H_ 8
#define HD_ 64
#define D_ 1024

static constexpr float SCALING_C = 0.125f;                     // 64^-0.5
static constexpr float LAMBDA_INIT_C = 0.35550906759096966f;   // 0.8 - 0.6*exp(-0.3)

typedef float f32x4 __attribute__((ext_vector_type(4)));
typedef float f32x2 __attribute__((ext_vector_type(2)));
typedef short bf16x8 __attribute__((ext_vector_type(8)));

static __device__ __forceinline__ short f2bf(float f) {
    unsigned u = __builtin_bit_cast(unsigned, f);
    unsigned r = (u + 0x7fffu + ((u >> 16) & 1u)) >> 16;   // RNE
    return (short)r;
}

// ---------- lam = exp(lq1.lk1) - exp(lq2.lk2) + LAMBDA_INIT ----------
__global__ void k_lam(const float* __restrict__ lq1, const float* __restrict__ lk1,
                      const float* __restrict__ lq2, const float* __restrict__ lk2,
                      float* __restrict__ lam) {
    int l = threadIdx.x;  // 64
    float v1 = lq1[l] * lk1[l];
    float v2 = lq2[l] * lk2[l];
    #pragma unroll
    for (int o = 32; o > 0; o >>= 1) { v1 += __shfl_xor(v1, o); v2 += __shfl_xor(v2, o); }
    if (l == 0) lam[0] = expf(v1) - expf(v2) + LAMBDA_INIT_C;
}

// ---------- Qhat[b, j] = SCALING * sum_e query[b,e] * Wq[e, j] ----------
__global__ __launch_bounds__(256) void k_qhat(const float* __restrict__ query,
                                              const float* __restrict__ Wq,
                                              float* __restrict__ qhat) {
    int b = blockIdx.y;
    int j = blockIdx.x * 256 + threadIdx.x;
    int t = threadIdx.x;
    __shared__ float q[E_];
    q[t] = query[b * E_ + t];
    q[t + 256] = query[b * E_ + t + 256];
    __syncthreads();
    float acc = 0.f;
    #pragma unroll 4
    for (int e = 0; e < E_; ++e) acc += q[e] * Wq[(long)e * D_ + j];
    qhat[b * D_ + j] = acc * SCALING_C;
}

// ---------- qk[b,hs,e] = sum_d Qhat[b,hs*64+d] * Wk[e, hs*64+d], stored in
// ---------- MFMA B-fragment order: frag[b][step][lane][j] (bf16) ----------
__global__ __launch_bounds__(64) void k_qk(const float* __restrict__ qhat,
                                           const float* __restrict__ Wk,
                                           unsigned short* __restrict__ qkfrag) {
    int hs = blockIdx.x, b = blockIdx.y;
    int l = threadIdx.x;  // 64
    __shared__ float qh[HD_];
    qh[l] = qhat[b * D_ + hs * HD_ + l];
    __syncthreads();
    int e0 = l * 8;
    float acc[8];
    #pragma unroll
    for (int j = 0; j < 8; ++j) {
        const f32x4* w = (const f32x4*)(Wk + (long)(e0 + j) * D_ + hs * HD_);
        float s = 0.f;
        #pragma unroll
        for (int d4 = 0; d4 < HD_ / 4; ++d4) {
            f32x4 wv = w[d4];
            s += qh[d4 * 4 + 0] * wv[0] + qh[d4 * 4 + 1] * wv[1]
               + qh[d4 * 4 + 2] * wv[2] + qh[d4 * 4 + 3] * wv[3];
        }
        acc[j] = s;
    }
    // e = e0 + j ; step = e/32 ; kk = e%32 ; fraglane = (kk/8)*16 + hs ; pos j = e%8
    bf16x8 v;
    #pragma unroll
    for (int j = 0; j < 8; ++j) v[j] = f2bf(acc[j]);
    int s_ = l >> 2;                // e0/32
    int ll = (l & 3) * 16 + hs;
    *(bf16x8*)(qkfrag + (((long)b * 16 + s_) * 64 + ll) * 8) = v;
}

// ---------- scores[b,hs,p] = sum_e key[b,p,e]*qk[b,hs,e]  via MFMA 16x16x32 ----------
// A-frag: lane holds key[p0 + (l&15)][32s + 8*(l>>4) + 0..7]  (global->reg->bf16)
// B-frag: preloaded from qkfrag (already in lane order)
// C:      row p = (l>>4)*4 + r, col hs = l&15   [verified layout]
__global__ __launch_bounds__(256) void k_scores(const float* __restrict__ key,
                                                const unsigned short* __restrict__ qkfrag,
                                                float* __restrict__ scores) {
    int b = blockIdx.y;
    int wv = threadIdx.x >> 6, l = threadIdx.x & 63;
    int p0 = blockIdx.x * 64 + wv * 16;
    const bf16x8* qf = (const bf16x8*)(qkfrag + (long)b * 16 * 64 * 8);
    bf16x8 bfr[16];
    #pragma unroll
    for (int s = 0; s < 16; ++s) bfr[s] = qf[s * 64 + l];
    f32x4 acc = {0.f, 0.f, 0.f, 0.f};
    int row = p0 + (l & 15);
    const float* kp = key + ((long)b * P_ + row) * E_ + (l >> 4) * 8;
    #pragma unroll
    for (int s = 0; s < 16; ++s) {
        f32x4 x0 = *(const f32x4*)(kp + s * 32);
        f32x4 x1 = *(const f32x4*)(kp + s * 32 + 4);
        bf16x8 a;
        a[0] = f2bf(x0[0]); a[1] = f2bf(x0[1]); a[2] = f2bf(x0[2]); a[3] = f2bf(x0[3]);
        a[4] = f2bf(x1[0]); a[5] = f2bf(x1[1]); a[6] = f2bf(x1[2]); a[7] = f2bf(x1[3]);
        acc = __builtin_amdgcn_mfma_f32_16x16x32_bf16(a, bfr[s], acc, 0, 0, 0);
    }
    int hs = l & 15;
    int pr = p0 + (l >> 4) * 4;
    *(f32x4*)(scores + ((long)b * 16 + hs) * P_ + pr) = acc;
}

// ---------- softmax rows (s=0,1) + diff = sm0 - lam*sm1 -> out1 ----------
__global__ __launch_bounds__(256) void k_softmax(const float* __restrict__ scores,
                                                 const float* __restrict__ lamp,
                                                 float* __restrict__ out1) {
    int h = blockIdx.x, b = blockIdx.y;
    int t = threadIdx.x, wv = t >> 6, ln = t & 63;
    __shared__ __align__(16) float r0[P_];
    __shared__ __align__(16) float r1[P_];
    __shared__ float redm0[4], redm1[4], redz0[4], redz1[4];
    const float* s0 = scores + ((long)b * 16 + 2 * h) * P_;
    const float* s1 = s0 + P_;
    float m0 = -3.0e38f, m1 = -3.0e38f;
    for (int i = t; i < P_ / 4; i += 256) {
        f32x4 a = ((const f32x4*)s0)[i];
        f32x4 c = ((const f32x4*)s1)[i];
        ((f32x4*)r0)[i] = a;
        ((f32x4*)r1)[i] = c;
        #pragma unroll
        for (int q = 0; q < 4; ++q) { m0 = fmaxf(m0, a[q]); m1 = fmaxf(m1, c[q]); }
    }
    #pragma unroll
    for (int o = 32; o > 0; o >>= 1) { m0 = fmaxf(m0, __shfl_xor(m0, o)); m1 = fmaxf(m1, __shfl_xor(m1, o)); }
    if (ln == 0) { redm0[wv] = m0; redm1[wv] = m1; }
    __syncthreads();
    m0 = fmaxf(fmaxf(redm0[0], redm0[1]), fmaxf(redm0[2], redm0[3]));
    m1 = fmaxf(fmaxf(redm1[0], redm1[1]), fmaxf(redm1[2], redm1[3]));
    float z0 = 0.f, z1 = 0.f;
    for (int i = t; i < P_ / 4; i += 256) {
        f32x4 a = ((f32x4*)r0)[i];
        f32x4 c = ((f32x4*)r1)[i];
        #pragma unroll
        for (int q = 0; q < 4; ++q) {
            a[q] = expf(a[q] - m0); c[q] = expf(c[q] - m1);
            z0 += a[q]; z1 += c[q];
        }
        ((f32x4*)r0)[i] = a;
        ((f32x4*)r1)[i] = c;
    }
    #pragma unroll
    for (int o = 32; o > 0; o >>= 1) { z0 += __shfl_xor(z0, o); z1 += __shfl_xor(z1, o); }
    if (ln == 0) { redz0[wv] = z0; redz1[wv] = z1; }
    __syncthreads();
    z0 = redz0[0] + redz0[1] + redz0[2] + redz0[3];
    z1 = redz1[0] + redz1[1] + redz1[2] + redz1[3];
    float lam = lamp[0];
    float i0 = 1.f / (z0 + 1e-20f);
    float i1 = lam / (z1 + 1e-20f);
    float* dst = out1 + ((long)b * H_ + h) * P_;
    for (int i = t; i < P_ / 4; i += 256) {
        f32x4 a = ((f32x4*)r0)[i];
        f32x4 c = ((f32x4*)r1)[i];
        f32x4 d;
        #pragma unroll
        for (int q = 0; q < 4; ++q) d[q] = a[q] * i0 - c[q] * i1;
        ((f32x4*)dst)[i] = d;
    }
}

// ---------- attk partials: part[pc][b][h][e] = sum_{p in chunk} diff[b,h,p]*key[b,p,e] ----------
__global__ __launch_bounds__(256) void k_attk(const float* __restrict__ key,
                                              const float* __restrict__ diff,
                                              float* __restrict__ part) {
    int pc = blockIdx.x, b = blockIdx.y;
    int t = threadIdx.x;
    __shared__ __align__(16) float w[H_][256];
    for (int i = t; i < H_ * 256; i += 256) {
        int hh = i >> 8, p = i & 255;
        w[hh][p] = diff[((long)b * H_ + hh) * P_ + pc * 256 + p];
    }
    __syncthreads();
    int e = t * 2;
    const float* kp = key + ((long)b * P_ + pc * 256) * E_ + e;
    float ax[8] = {0.f,0.f,0.f,0.f,0.f,0.f,0.f,0.f};
    float ay[8] = {0.f,0.f,0.f,0.f,0.f,0.f,0.f,0.f};
    for (int p4 = 0; p4 < 256; p4 += 4) {
        f32x4 wv[8];
        #pragma unroll
        for (int hh = 0; hh < 8; ++hh) wv[hh] = *(const f32x4*)&w[hh][p4];
        #pragma unroll
        for (int q = 0; q < 4; ++q) {
            f32x2 kv = *(const f32x2*)(kp + (long)(p4 + q) * E_);
            #pragma unroll
            for (int hh = 0; hh < 8; ++hh) { ax[hh] += wv[hh][q] * kv[0]; ay[hh] += wv[hh][q] * kv[1]; }
        }
    }
    float* dst = part + ((long)pc * B_ + b) * (H_ * E_) + e;
    #pragma unroll
    for (int hh = 0; hh < 8; ++hh) {
        f32x2 o; o[0] = ax[hh]; o[1] = ay[hh];
        *(f32x2*)(dst + hh * E_) = o;
    }
}

// ---------- final: reduce partials, out_pre = attk @ Wv-slices, RMSNorm, @ Wo ----------
__global__ __launch_bounds__(256) void k_final(const float* __restrict__ part,
                                               const float* __restrict__ Wv,
                                               const float* __restrict__ rmsw,
                                               const float* __restrict__ Wo,
                                               float* __restrict__ out0) {
    int b = blockIdx.x, t = threadIdx.x;
    __shared__ float attk[H_ * E_];
    __shared__ float on[D_];
    __shared__ float rms[H_];
    for (int i = t; i < H_ * E_; i += 256) {
        float s = 0.f;
        #pragma unroll
        for (int c = 0; c < 8; ++c) s += part[((long)c * B_ + b) * (H_ * E_) + i];
        attk[i] = s;
    }
    __syncthreads();
    for (int j = t; j < D_; j += 256) {
        int hh = j >> 7;                      // j = h*128 + d2
        const float* a = attk + hh * E_;
        const float* w = Wv + j;
        float s = 0.f;
        #pragma unroll 4
        for (int e = 0; e < E_; ++e) s += a[e] * w[(long)e * D_];
        on[j] = s;
    }
    __syncthreads();
    if (t < 128) {
        int hh = t >> 4, g = t & 15;
        const float* o = on + hh * 128;
        float s = 0.f;
        #pragma unroll
        for (int k = 0; k < 8; ++k) { float v = o[g + 16 * k]; s += v * v; }
        #pragma unroll
        for (int o2 = 8; o2 > 0; o2 >>= 1) s += __shfl_xor(s, o2);
        if (g == 0) rms[hh] = s;
    }
    __syncthreads();
    for (int j = t; j < D_; j += 256) {
        int hh = j >> 7;
        float scale = rsqrtf(rms[hh] * (1.f / 128.f) + 1e-5f) * rmsw[j & 127] * (1.f - LAMBDA_INIT_C);
        on[j] *= scale;
    }
    __syncthreads();
    float a0 = 0.f, a1 = 0.f;
    #pragma unroll 4
    for (int k = 0; k < D_; ++k) {
        float v = on[k];
        a0 += v * Wo[(long)k * 512 + t];
        a1 += v * Wo[(long)k * 512 + t + 256];
    }
    out0[(long)b * 512 + t] = a0;
    out0[(long)b * 512 + t + 256] = a1;
}

extern "C" void kernel_launch(void* const* d_in, const int* in_sizes, int n_in,
                              void* d_out, int out_size, void* d_ws, size_t ws_size,
                              hipStream_t stream) {
    const float* query = (const float*)d_in[0];
    const float* key   = (const float*)d_in[1];
    const float* Wq    = (const float*)d_in[2];
    const float* Wk    = (const float*)d_in[3];
    const float* Wv    = (const float*)d_in[4];
    const float* Wo    = (const float*)d_in[5];
    const float* lq1   = (const float*)d_in[6];
    const float* lk1   = (const float*)d_in[7];
    const float* lq2   = (const float*)d_in[8];
    const float* lk2   = (const float*)d_in[9];
    const float* rmsw  = (const float*)d_in[10];

    float* out0 = (float*)d_out;           // [64,1,512]
    float* out1 = out0 + B_ * E_;          // diff_attn [64,8,1,2048]

    // workspace layout (floats): qhat[65536] | lam[pad 64] | scores(=part alias)[2097152] | qkfrag(bf16)[524288]
    float* qhat   = (float*)d_ws;
    float* lam    = qhat + 65536;
    float* scores = qhat + 65600;
    float* part   = scores;                                 // reused after softmax consumed scores
    unsigned short* qkfrag = (unsigned short*)(scores + (long)16 * B_ * P_);

    hipLaunchKernelGGL(k_lam,     dim3(1),      dim3(64),  0, stream, lq1, lk1, lq2, lk2, lam);
    hipLaunchKernelGGL(k_qhat,    dim3(4, B_),  dim3(256), 0, stream, query, Wq, qhat);
    hipLaunchKernelGGL(k_qk,      dim3(16, B_), dim3(64),  0, stream, qhat, Wk, qkfrag);
    hipLaunchKernelGGL(k_scores,  dim3(32, B_), dim3(256), 0, stream, key, qkfrag, scores);
    hipLaunchKernelGGL(k_softmax, dim3(H_, B_), dim3(256), 0, stream, scores, lam, out1);
    hipLaunchKernelGGL(k_attk,    dim3(8, B_),  dim3(256), 0, stream, key, out1, part);
    hipLaunchKernelGGL(k_final,   dim3(B_),     dim3(256), 0, stream, part, Wv, rmsw, Wo, out0);
}

// Round 2
// 220.699 us; speedup vs baseline: 2.4782x; 2.4782x over previous
//
#include <hip/hip_runtime.h>
#include <hip/hip_bf16.h>
#include <math.h>

#define B_ 64
#define P_ 2048
#define E_ 512
#define H_ 8
#define HD_ 64
#define D_ 1024

static constexpr float SCALING_C = 0.125f;                     // 64^-0.5
static constexpr float LAMBDA_INIT_C = 0.35550906759096966f;   // 0.8 - 0.6*exp(-0.3)

typedef float f32x4 __attribute__((ext_vector_type(4)));
typedef float f32x2 __attribute__((ext_vector_type(2)));
typedef short bf16x8 __attribute__((ext_vector_type(8)));

static __device__ __forceinline__ short f2bf(float f) {
    unsigned u = __builtin_bit_cast(unsigned, f);
    unsigned r = (u + 0x7fffu + ((u >> 16) & 1u)) >> 16;   // RNE
    return (short)r;
}

// ---------- lam = exp(lq1.lk1) - exp(lq2.lk2) + LAMBDA_INIT ----------
__global__ void k_lam(const float* __restrict__ lq1, const float* __restrict__ lk1,
                      const float* __restrict__ lq2, const float* __restrict__ lk2,
                      float* __restrict__ lam) {
    int l = threadIdx.x;  // 64
    float v1 = lq1[l] * lk1[l];
    float v2 = lq2[l] * lk2[l];
    #pragma unroll
    for (int o = 32; o > 0; o >>= 1) { v1 += __shfl_xor(v1, o); v2 += __shfl_xor(v2, o); }
    if (l == 0) lam[0] = expf(v1) - expf(v2) + LAMBDA_INIT_C;
}

// ---------- Qhat[b, j] = SCALING * sum_e query[b,e] * Wq[e, j] ----------
__global__ __launch_bounds__(256) void k_qhat(const float* __restrict__ query,
                                              const float* __restrict__ Wq,
                                              float* __restrict__ qhat) {
    int b = blockIdx.y;
    int j = blockIdx.x * 256 + threadIdx.x;
    int t = threadIdx.x;
    __shared__ float q[E_];
    q[t] = query[b * E_ + t];
    q[t + 256] = query[b * E_ + t + 256];
    __syncthreads();
    float acc = 0.f;
    #pragma unroll 4
    for (int e = 0; e < E_; ++e) acc += q[e] * Wq[(long)e * D_ + j];
    qhat[b * D_ + j] = acc * SCALING_C;
}

// ---------- qk[b,hs,e] = sum_d Qhat[b,hs*64+d] * Wk[e, hs*64+d], stored in
// ---------- MFMA B-fragment order: frag[b][step][lane][j] (bf16) ----------
__global__ __launch_bounds__(64) void k_qk(const float* __restrict__ qhat,
                                           const float* __restrict__ Wk,
                                           unsigned short* __restrict__ qkfrag) {
    int hs = blockIdx.x, b = blockIdx.y;
    int l = threadIdx.x;  // 64
    __shared__ float qh[HD_];
    qh[l] = qhat[b * D_ + hs * HD_ + l];
    __syncthreads();
    int e0 = l * 8;
    float acc[8];
    #pragma unroll
    for (int j = 0; j < 8; ++j) {
        const f32x4* w = (const f32x4*)(Wk + (long)(e0 + j) * D_ + hs * HD_);
        float s = 0.f;
        #pragma unroll
        for (int d4 = 0; d4 < HD_ / 4; ++d4) {
            f32x4 wv = w[d4];
            s += qh[d4 * 4 + 0] * wv[0] + qh[d4 * 4 + 1] * wv[1]
               + qh[d4 * 4 + 2] * wv[2] + qh[d4 * 4 + 3] * wv[3];
        }
        acc[j] = s;
    }
    bf16x8 v;
    #pragma unroll
    for (int j = 0; j < 8; ++j) v[j] = f2bf(acc[j]);
    int s_ = l >> 2;                // e0/32
    int ll = (l & 3) * 16 + hs;
    *(bf16x8*)(qkfrag + (((long)b * 16 + s_) * 64 + ll) * 8) = v;
}

// ---------- scores[b,hs,p] = sum_e key[b,p,e]*qk[b,hs,e]  via MFMA 16x16x32 ----------
__global__ __launch_bounds__(256) void k_scores(const float* __restrict__ key,
                                                const unsigned short* __restrict__ qkfrag,
                                                float* __restrict__ scores) {
    int b = blockIdx.y;
    int wv = threadIdx.x >> 6, l = threadIdx.x & 63;
    int p0 = blockIdx.x * 64 + wv * 16;
    const bf16x8* qf = (const bf16x8*)(qkfrag + (long)b * 16 * 64 * 8);
    bf16x8 bfr[16];
    #pragma unroll
    for (int s = 0; s < 16; ++s) bfr[s] = qf[s * 64 + l];
    f32x4 acc = {0.f, 0.f, 0.f, 0.f};
    int row = p0 + (l & 15);
    const float* kp = key + ((long)b * P_ + row) * E_ + (l >> 4) * 8;
    #pragma unroll
    for (int s = 0; s < 16; ++s) {
        f32x4 x0 = *(const f32x4*)(kp + s * 32);
        f32x4 x1 = *(const f32x4*)(kp + s * 32 + 4);
        bf16x8 a;
        a[0] = f2bf(x0[0]); a[1] = f2bf(x0[1]); a[2] = f2bf(x0[2]); a[3] = f2bf(x0[3]);
        a[4] = f2bf(x1[0]); a[5] = f2bf(x1[1]); a[6] = f2bf(x1[2]); a[7] = f2bf(x1[3]);
        acc = __builtin_amdgcn_mfma_f32_16x16x32_bf16(a, bfr[s], acc, 0, 0, 0);
    }
    int hs = l & 15;
    int pr = p0 + (l >> 4) * 4;
    *(f32x4*)(scores + ((long)b * 16 + hs) * P_ + pr) = acc;
}

// ---------- softmax rows (s=0,1) + diff = sm0 - lam*sm1 -> out1 ----------
__global__ __launch_bounds__(256) void k_softmax(const float* __restrict__ scores,
                                                 const float* __restrict__ lamp,
                                                 float* __restrict__ out1) {
    int h = blockIdx.x, b = blockIdx.y;
    int t = threadIdx.x, wv = t >> 6, ln = t & 63;
    __shared__ __align__(16) float r0[P_];
    __shared__ __align__(16) float r1[P_];
    __shared__ float redm0[4], redm1[4], redz0[4], redz1[4];
    const float* s0 = scores + ((long)b * 16 + 2 * h) * P_;
    const float* s1 = s0 + P_;
    float m0 = -3.0e38f, m1 = -3.0e38f;
    for (int i = t; i < P_ / 4; i += 256) {
        f32x4 a = ((const f32x4*)s0)[i];
        f32x4 c = ((const f32x4*)s1)[i];
        ((f32x4*)r0)[i] = a;
        ((f32x4*)r1)[i] = c;
        #pragma unroll
        for (int q = 0; q < 4; ++q) { m0 = fmaxf(m0, a[q]); m1 = fmaxf(m1, c[q]); }
    }
    #pragma unroll
    for (int o = 32; o > 0; o >>= 1) { m0 = fmaxf(m0, __shfl_xor(m0, o)); m1 = fmaxf(m1, __shfl_xor(m1, o)); }
    if (ln == 0) { redm0[wv] = m0; redm1[wv] = m1; }
    __syncthreads();
    m0 = fmaxf(fmaxf(redm0[0], redm0[1]), fmaxf(redm0[2], redm0[3]));
    m1 = fmaxf(fmaxf(redm1[0], redm1[1]), fmaxf(redm1[2], redm1[3]));
    float z0 = 0.f, z1 = 0.f;
    for (int i = t; i < P_ / 4; i += 256) {
        f32x4 a = ((f32x4*)r0)[i];
        f32x4 c = ((f32x4*)r1)[i];
        #pragma unroll
        for (int q = 0; q < 4; ++q) {
            a[q] = expf(a[q] - m0); c[q] = expf(c[q] - m1);
            z0 += a[q]; z1 += c[q];
        }
        ((f32x4*)r0)[i] = a;
        ((f32x4*)r1)[i] = c;
    }
    #pragma unroll
    for (int o = 32; o > 0; o >>= 1) { z0 += __shfl_xor(z0, o); z1 += __shfl_xor(z1, o); }
    if (ln == 0) { redz0[wv] = z0; redz1[wv] = z1; }
    __syncthreads();
    z0 = redz0[0] + redz0[1] + redz0[2] + redz0[3];
    z1 = redz1[0] + redz1[1] + redz1[2] + redz1[3];
    float lam = lamp[0];
    float i0 = 1.f / (z0 + 1e-20f);
    float i1 = lam / (z1 + 1e-20f);
    float* dst = out1 + ((long)b * H_ + h) * P_;
    for (int i = t; i < P_ / 4; i += 256) {
        f32x4 a = ((f32x4*)r0)[i];
        f32x4 c = ((f32x4*)r1)[i];
        f32x4 d;
        #pragma unroll
        for (int q = 0; q < 4; ++q) d[q] = a[q] * i0 - c[q] * i1;
        ((f32x4*)dst)[i] = d;
    }
}

// ---------- attk partials: part[pc][b][h][e] = sum_{p in chunk} diff[b,h,p]*key[b,p,e] ----------
__global__ __launch_bounds__(256) void k_attk(const float* __restrict__ key,
                                              const float* __restrict__ diff,
                                              float* __restrict__ part) {
    int pc = blockIdx.x, b = blockIdx.y;
    int t = threadIdx.x;
    __shared__ __align__(16) float w[H_][256];
    for (int i = t; i < H_ * 256; i += 256) {
        int hh = i >> 8, p = i & 255;
        w[hh][p] = diff[((long)b * H_ + hh) * P_ + pc * 256 + p];
    }
    __syncthreads();
    int e = t * 2;
    const float* kp = key + ((long)b * P_ + pc * 256) * E_ + e;
    float ax[8] = {0.f,0.f,0.f,0.f,0.f,0.f,0.f,0.f};
    float ay[8] = {0.f,0.f,0.f,0.f,0.f,0.f,0.f,0.f};
    for (int p4 = 0; p4 < 256; p4 += 4) {
        f32x4 wv[8];
        #pragma unroll
        for (int hh = 0; hh < 8; ++hh) wv[hh] = *(const f32x4*)&w[hh][p4];
        #pragma unroll
        for (int q = 0; q < 4; ++q) {
            f32x2 kv = *(const f32x2*)(kp + (long)(p4 + q) * E_);
            #pragma unroll
            for (int hh = 0; hh < 8; ++hh) { ax[hh] += wv[hh][q] * kv[0]; ay[hh] += wv[hh][q] * kv[1]; }
        }
    }
    float* dst = part + ((long)pc * B_ + b) * (H_ * E_) + e;
    #pragma unroll
    for (int hh = 0; hh < 8; ++hh) {
        f32x2 o; o[0] = ax[hh]; o[1] = ay[hh];
        *(f32x2*)(dst + hh * E_) = o;
    }
}

// ---------- per (b,h): reduce partials, on = attk @ Wv-slice, RMSNorm, scale ----------
__global__ __launch_bounds__(256) void k_ovrms(const float* __restrict__ part,
                                               const float* __restrict__ Wv,
                                               const float* __restrict__ rmsw,
                                               float* __restrict__ on_out) {
    int h = blockIdx.x, b = blockIdx.y;
    int t = threadIdx.x;
    __shared__ float attk[E_];
    __shared__ float onred[2][128];
    __shared__ float red[4];
    for (int i = t; i < E_; i += 256) {
        float s = 0.f;
        #pragma unroll
        for (int c = 0; c < 8; ++c) s += part[((long)c * B_ + b) * (H_ * E_) + h * E_ + i];
        attk[i] = s;
    }
    __syncthreads();
    int j = t & 127, half = t >> 7;
    const float* w = Wv + (long)(half * 256) * D_ + h * 128 + j;
    const float* a = attk + half * 256;
    float s0 = 0.f, s1 = 0.f, s2 = 0.f, s3 = 0.f;
    #pragma unroll 8
    for (int e = 0; e < 256; e += 4) {
        s0 += a[e]     * w[(long)e * D_];
        s1 += a[e + 1] * w[(long)(e + 1) * D_];
        s2 += a[e + 2] * w[(long)(e + 2) * D_];
        s3 += a[e + 3] * w[(long)(e + 3) * D_];
    }
    onred[half][j] = (s0 + s1) + (s2 + s3);
    __syncthreads();
    float v = 0.f;
    if (t < 128) v = onred[0][t] + onred[1][t];
    float sq = v * v;
    int wv = t >> 6, ln = t & 63;
    #pragma unroll
    for (int o = 32; o > 0; o >>= 1) sq += __shfl_xor(sq, o);
    if (ln == 0) red[wv] = sq;
    __syncthreads();
    float tot = red[0] + red[1];
    float scale = rsqrtf(tot * (1.f / 128.f) + 1e-5f) * (1.f - LAMBDA_INIT_C);
    if (t < 128) on_out[(long)b * D_ + h * 128 + t] = v * scale * rmsw[t];
}

// ---------- Wo split-K partials: wop[kc][b][o] ----------
__global__ __launch_bounds__(256) void k_wo(const float* __restrict__ on,
                                            const float* __restrict__ Wo,
                                            float* __restrict__ wop) {
    int kc = blockIdx.x >> 1, oc = blockIdx.x & 1, b = blockIdx.y;
    int t = threadIdx.x;
    __shared__ float sh[256];
    sh[t] = on[(long)b * D_ + kc * 256 + t];
    __syncthreads();
    int o = oc * 256 + t;
    const float* w = Wo + (long)(kc * 256) * 512 + o;
    float s0 = 0.f, s1 = 0.f, s2 = 0.f, s3 = 0.f;
    #pragma unroll 8
    for (int k = 0; k < 256; k += 4) {
        s0 += sh[k]     * w[(long)k * 512];
        s1 += sh[k + 1] * w[(long)(k + 1) * 512];
        s2 += sh[k + 2] * w[(long)(k + 2) * 512];
        s3 += sh[k + 3] * w[(long)(k + 3) * 512];
    }
    wop[((long)kc * B_ + b) * 512 + o] = (s0 + s1) + (s2 + s3);
}

// ---------- reduce Wo partials -> out0 ----------
__global__ __launch_bounds__(256) void k_wored(const float* __restrict__ wop,
                                               float* __restrict__ out0) {
    int b = blockIdx.x, t = threadIdx.x;
    #pragma unroll
    for (int i = 0; i < 2; ++i) {
        int o = i * 256 + t;
        float s = 0.f;
        #pragma unroll
        for (int kc = 0; kc < 4; ++kc) s += wop[((long)kc * B_ + b) * 512 + o];
        out0[(long)b * 512 + o] = s;
    }
}

extern "C" void kernel_launch(void* const* d_in, const int* in_sizes, int n_in,
                              void* d_out, int out_size, void* d_ws, size_t ws_size,
                              hipStream_t stream) {
    const float* query = (const float*)d_in[0];
    const float* key   = (const float*)d_in[1];
    const float* Wq    = (const float*)d_in[2];
    const float* Wk    = (const float*)d_in[3];
    const float* Wv    = (const float*)d_in[4];
    const float* Wo    = (const float*)d_in[5];
    const float* lq1   = (const float*)d_in[6];
    const float* lk1   = (const float*)d_in[7];
    const float* lq2   = (const float*)d_in[8];
    const float* lk2   = (const float*)d_in[9];
    const float* rmsw  = (const float*)d_in[10];

    float* out0 = (float*)d_out;           // [64,1,512]
    float* out1 = out0 + B_ * E_;          // diff_attn [64,8,1,2048]

    // ws layout (floats): qhat[65536] | lam[64] | scores/part[2097152] |
    //                     qkfrag(bf16=262144 floats) | on[65536] | wop[131072]
    float* qhat   = (float*)d_ws;
    float* lam    = qhat + 65536;
    float* scores = qhat + 65600;
    float* part   = scores;                                 // reused after softmax consumed scores
    unsigned short* qkfrag = (unsigned short*)(scores + (long)16 * B_ * P_);
    float* on     = scores + (long)16 * B_ * P_ + 262144;
    float* wop    = on + 65536;

    hipLaunchKernelGGL(k_lam,     dim3(1),      dim3(64),  0, stream, lq1, lk1, lq2, lk2, lam);
    hipLaunchKernelGGL(k_qhat,    dim3(4, B_),  dim3(256), 0, stream, query, Wq, qhat);
    hipLaunchKernelGGL(k_qk,      dim3(16, B_), dim3(64),  0, stream, qhat, Wk, qkfrag);
    hipLaunchKernelGGL(k_scores,  dim3(32, B_), dim3(256), 0, stream, key, qkfrag, scores);
    hipLaunchKernelGGL(k_softmax, dim3(H_, B_), dim3(256), 0, stream, scores, lam, out1);
    hipLaunchKernelGGL(k_attk,    dim3(8, B_),  dim3(256), 0, stream, key, out1, part);
    hipLaunchKernelGGL(k_ovrms,   dim3(H_, B_), dim3(256), 0, stream, part, Wv, rmsw, on);
    hipLaunchKernelGGL(k_wo,      dim3(8, B_),  dim3(256), 0, stream, on, Wo, wop);
    hipLaunchKernelGGL(k_wored,   dim3(B_),     dim3(256), 0, stream, wop, out0);
}

// Round 3
// 171.525 us; speedup vs baseline: 3.1886x; 1.2867x over previous
//
#include <hip/hip_runtime.h>
#include <hip/hip_bf16.h>
#include <math.h>

#define B_ 64
#define P_ 2048
#define E_ 512
#define H_ 8
#define HD_ 64
#define D_ 1024
#define NC_ 8      // p-chunks
#define CP_ 256    // p per chunk
#define WPAD 260   // padded LDS row stride (floats)

static constexpr float SCALING_C = 0.125f;                     // 64^-0.5
static constexpr float LAMBDA_INIT_C = 0.35550906759096966f;   // 0.8 - 0.6*exp(-0.3)

typedef float f32x4 __attribute__((ext_vector_type(4)));
typedef float f32x2 __attribute__((ext_vector_type(2)));
typedef short bf16x8 __attribute__((ext_vector_type(8)));

static __device__ __forceinline__ short f2bf(float f) {
    unsigned u = __builtin_bit_cast(unsigned, f);
    unsigned r = (u + 0x7fffu + ((u >> 16) & 1u)) >> 16;   // RNE
    return (short)r;
}

// ---------- qproj: qhat slice (4 heads' worth of j) then qk fragments ----------
// grid (4, B): block x owns hs = 4x..4x+3  (j range x*256..x*256+255)
__global__ __launch_bounds__(256) void k_qproj(const float* __restrict__ query,
                                               const float* __restrict__ Wq,
                                               const float* __restrict__ Wk,
                                               unsigned short* __restrict__ qkfrag) {
    int x = blockIdx.x, b = blockIdx.y, t = threadIdx.x;
    __shared__ float q[E_];
    __shared__ float qh[256];
    q[t] = query[b * E_ + t];
    q[t + 256] = query[b * E_ + t + 256];
    __syncthreads();
    {
        int j = x * 256 + t;
        const float* w = Wq + j;
        float s0 = 0.f, s1 = 0.f, s2 = 0.f, s3 = 0.f;
        #pragma unroll 4
        for (int e = 0; e < E_; e += 4) {
            s0 += q[e]     * w[(long)e * D_];
            s1 += q[e + 1] * w[(long)(e + 1) * D_];
            s2 += q[e + 2] * w[(long)(e + 2) * D_];
            s3 += q[e + 3] * w[(long)(e + 3) * D_];
        }
        qh[t] = ((s0 + s1) + (s2 + s3)) * SCALING_C;
    }
    __syncthreads();
    int hs_loc = t >> 6, l = t & 63;
    int hs = x * 4 + hs_loc;
    int e0 = l * 8;
    const float* qp = qh + hs_loc * 64;
    float acc[8];
    #pragma unroll
    for (int jj = 0; jj < 8; ++jj) {
        const f32x4* w = (const f32x4*)(Wk + (long)(e0 + jj) * D_ + hs * HD_);
        float s = 0.f;
        #pragma unroll
        for (int d4 = 0; d4 < 16; ++d4) {
            f32x4 wv = w[d4];
            s += qp[d4 * 4 + 0] * wv[0] + qp[d4 * 4 + 1] * wv[1]
               + qp[d4 * 4 + 2] * wv[2] + qp[d4 * 4 + 3] * wv[3];
        }
        acc[jj] = s;
    }
    bf16x8 v;
    #pragma unroll
    for (int jj = 0; jj < 8; ++jj) v[jj] = f2bf(acc[jj]);
    // e = e0+jj ; step = e/32 ; lane = ((e%32)/8)*16 + hs ; pos = e%8
    *(bf16x8*)(qkfrag + (((long)b * 16 + (l >> 2)) * 64 + (l & 3) * 16 + hs) * 8) = v;
}

// ---------- fused: scores (MFMA) + chunk-local softmax stats + exp-weighted key partials ----------
// grid (NC_, B), 256 thr = 4 waves; each block owns 256 p-rows, all 16 hs.
__global__ __launch_bounds__(256) void k_fused(const float* __restrict__ key,
                                               const unsigned short* __restrict__ qkfrag,
                                               float* __restrict__ wexp,
                                               float* __restrict__ ms, float* __restrict__ zs,
                                               float* __restrict__ apart) {
    int pc = blockIdx.x, b = blockIdx.y;
    int t = threadIdx.x, wv = t >> 6, l = t & 63;
    __shared__ float wlds[16][WPAD];

    // phase A: scores via MFMA 16x16x32, key global->reg->bf16
    const bf16x8* qf = (const bf16x8*)(qkfrag + (long)b * 16 * 64 * 8);
    bf16x8 bfr[16];
    #pragma unroll
    for (int s = 0; s < 16; ++s) bfr[s] = qf[s * 64 + l];
    #pragma unroll
    for (int rg = 0; rg < 4; ++rg) {
        int prow = wv * 64 + rg * 16 + (l & 15);
        const float* kp = key + ((long)b * P_ + pc * CP_ + prow) * E_ + (l >> 4) * 8;
        f32x4 acc = {0.f, 0.f, 0.f, 0.f};
        #pragma unroll
        for (int s = 0; s < 16; ++s) {
            f32x4 x0 = *(const f32x4*)(kp + s * 32);
            f32x4 x1 = *(const f32x4*)(kp + s * 32 + 4);
            bf16x8 a;
            a[0] = f2bf(x0[0]); a[1] = f2bf(x0[1]); a[2] = f2bf(x0[2]); a[3] = f2bf(x0[3]);
            a[4] = f2bf(x1[0]); a[5] = f2bf(x1[1]); a[6] = f2bf(x1[2]); a[7] = f2bf(x1[3]);
            acc = __builtin_amdgcn_mfma_f32_16x16x32_bf16(a, bfr[s], acc, 0, 0, 0);
        }
        int hs = l & 15;
        int p_loc = wv * 64 + rg * 16 + (l >> 4) * 4;
        *(f32x4*)&wlds[hs][p_loc] = acc;   // C layout: row p=(l>>4)*4+r, col hs=l&15
    }
    __syncthreads();

    // phase B: per-hs chunk max + exp + sum (16 lanes per hs, strided p)
    {
        int hsB = t >> 4, i = t & 15;
        float m = -3.0e38f;
        #pragma unroll
        for (int k = 0; k < 16; ++k) m = fmaxf(m, wlds[hsB][k * 16 + i]);
        #pragma unroll
        for (int o = 8; o > 0; o >>= 1) m = fmaxf(m, __shfl_xor(m, o));
        float z = 0.f;
        #pragma unroll
        for (int k = 0; k < 16; ++k) {
            float w = expf(wlds[hsB][k * 16 + i] - m);
            wlds[hsB][k * 16 + i] = w;
            z += w;
        }
        #pragma unroll
        for (int o = 8; o > 0; o >>= 1) z += __shfl_xor(z, o);
        if (i == 0) {
            ms[((long)pc * B_ + b) * 16 + hsB] = m;
            zs[((long)pc * B_ + b) * 16 + hsB] = z;
        }
    }
    __syncthreads();

    // write wexp (coalesced f32x4)
    #pragma unroll
    for (int k2 = 0; k2 < 4; ++k2) {
        int idx = k2 * 256 + t;          // f32x4 index over 16*256 floats
        int hh = idx >> 6;
        int p4 = (idx & 63) * 4;
        f32x4 wv4 = *(const f32x4*)&wlds[hh][p4];
        *(f32x4*)(wexp + ((long)b * 16 + hh) * P_ + pc * CP_ + p4) = wv4;
    }

    // phase C: apart[hs][e] = sum_p w[hs][p] * key[p][e]   (key rows L2-hot)
    {
        int e = t * 2;
        const float* kp2 = key + ((long)b * P_ + pc * CP_) * E_ + e;
        f32x2 a[16];
        #pragma unroll
        for (int hh = 0; hh < 16; ++hh) { a[hh][0] = 0.f; a[hh][1] = 0.f; }
        for (int p4 = 0; p4 < CP_; p4 += 4) {
            f32x4 wv4[16];
            #pragma unroll
            for (int hh = 0; hh < 16; ++hh) wv4[hh] = *(const f32x4*)&wlds[hh][p4];
            #pragma unroll
            for (int q = 0; q < 4; ++q) {
                f32x2 kv = *(const f32x2*)(kp2 + (long)(p4 + q) * E_);
                #pragma unroll
                for (int hh = 0; hh < 16; ++hh) a[hh] += kv * wv4[hh][q];
            }
        }
        #pragma unroll
        for (int hh = 0; hh < 16; ++hh)
            *(f32x2*)(apart + (((long)pc * B_ + b) * 16 + hh) * E_ + e) = a[hh];
    }
}

// ---------- combine: global softmax stats, out1 (diff), attk, OV, RMS -> on ----------
// grid (H, B), 256 thr
__global__ __launch_bounds__(256) void k_comb(const float* __restrict__ wexp,
                                              const float* __restrict__ ms, const float* __restrict__ zs,
                                              const float* __restrict__ apart,
                                              const float* __restrict__ lq1, const float* __restrict__ lk1,
                                              const float* __restrict__ lq2, const float* __restrict__ lk2,
                                              const float* __restrict__ Wv, const float* __restrict__ rmsw,
                                              float* __restrict__ out1, float* __restrict__ on) {
    int h = blockIdx.x, b = blockIdx.y, t = threadIdx.x;
    __shared__ float lam_s;
    __shared__ float attk[E_];
    __shared__ float onred[2][128];
    __shared__ float red[4];
    if (t < 64) {
        float v1 = lq1[t] * lk1[t];
        float v2 = lq2[t] * lk2[t];
        #pragma unroll
        for (int o = 32; o > 0; o >>= 1) { v1 += __shfl_xor(v1, o); v2 += __shfl_xor(v2, o); }
        if (t == 0) lam_s = expf(v1) - expf(v2) + LAMBDA_INIT_C;
    }
    __syncthreads();
    float lam = lam_s;
    int hs0 = 2 * h, hs1 = 2 * h + 1;
    float mc0[NC_], mc1[NC_], zc0[NC_], zc1[NC_];
    float m0 = -3.0e38f, m1 = -3.0e38f;
    #pragma unroll
    for (int c = 0; c < NC_; ++c) {
        mc0[c] = ms[((long)c * B_ + b) * 16 + hs0];
        mc1[c] = ms[((long)c * B_ + b) * 16 + hs1];
        zc0[c] = zs[((long)c * B_ + b) * 16 + hs0];
        zc1[c] = zs[((long)c * B_ + b) * 16 + hs1];
        m0 = fmaxf(m0, mc0[c]); m1 = fmaxf(m1, mc1[c]);
    }
    float z0 = 0.f, z1 = 0.f;
    #pragma unroll
    for (int c = 0; c < NC_; ++c) {
        z0 += zc0[c] * expf(mc0[c] - m0);
        z1 += zc1[c] * expf(mc1[c] - m1);
    }
    float i0 = 1.f / (z0 + 1e-20f);
    float i1 = lam / (z1 + 1e-20f);
    float c0[NC_], c1[NC_];
    #pragma unroll
    for (int c = 0; c < NC_; ++c) {
        c0[c] = expf(mc0[c] - m0) * i0;
        c1[c] = expf(mc1[c] - m1) * i1;
    }
    // out1 = diff
    const float* w0p = wexp + ((long)b * 16 + hs0) * P_;
    const float* w1p = wexp + ((long)b * 16 + hs1) * P_;
    float* dst = out1 + ((long)b * H_ + h) * P_;
    #pragma unroll
    for (int c = 0; c < NC_; ++c) {
        int p = c * CP_ + t;
        dst[p] = w0p[p] * c0[c] - w1p[p] * c1[c];
    }
    // attk
    #pragma unroll
    for (int k = 0; k < 2; ++k) {
        int e = k * 256 + t;
        float s = 0.f;
        #pragma unroll
        for (int c = 0; c < NC_; ++c) {
            s += c0[c] * apart[(((long)c * B_ + b) * 16 + hs0) * E_ + e]
               - c1[c] * apart[(((long)c * B_ + b) * 16 + hs1) * E_ + e];
        }
        attk[e] = s;
    }
    __syncthreads();
    // OV: on_pre[j] = sum_e attk[e] * Wv[e][h*128+j], split-K over e halves
    int j = t & 127, half = t >> 7;
    const float* w = Wv + (long)(half * 256) * D_ + h * 128 + j;
    const float* aa = attk + half * 256;
    float s0 = 0.f, s1 = 0.f, s2 = 0.f, s3 = 0.f;
    #pragma unroll 8
    for (int e = 0; e < 256; e += 4) {
        s0 += aa[e]     * w[(long)e * D_];
        s1 += aa[e + 1] * w[(long)(e + 1) * D_];
        s2 += aa[e + 2] * w[(long)(e + 2) * D_];
        s3 += aa[e + 3] * w[(long)(e + 3) * D_];
    }
    onred[half][j] = (s0 + s1) + (s2 + s3);
    __syncthreads();
    float v = 0.f;
    if (t < 128) v = onred[0][t] + onred[1][t];
    float sq = v * v;
    int wv2 = t >> 6, ln = t & 63;
    #pragma unroll
    for (int o = 32; o > 0; o >>= 1) sq += __shfl_xor(sq, o);
    if (ln == 0) red[wv2] = sq;
    __syncthreads();
    float tot = red[0] + red[1];
    float scale = rsqrtf(tot * (1.f / 128.f) + 1e-5f) * (1.f - LAMBDA_INIT_C);
    if (t < 128) on[(long)b * D_ + h * 128 + t] = v * scale * rmsw[t];
}

// ---------- Wo split-K partials: wop[kc][b][o] ----------
__global__ __launch_bounds__(256) void k_wo(const float* __restrict__ on,
                                            const float* __restrict__ Wo,
                                            float* __restrict__ wop) {
    int kc = blockIdx.x >> 1, oc = blockIdx.x & 1, b = blockIdx.y;
    int t = threadIdx.x;
    __shared__ float sh[256];
    sh[t] = on[(long)b * D_ + kc * 256 + t];
    __syncthreads();
    int o = oc * 256 + t;
    const float* w = Wo + (long)(kc * 256) * 512 + o;
    float s0 = 0.f, s1 = 0.f, s2 = 0.f, s3 = 0.f;
    #pragma unroll 8
    for (int k = 0; k < 256; k += 4) {
        s0 += sh[k]     * w[(long)k * 512];
        s1 += sh[k + 1] * w[(long)(k + 1) * 512];
        s2 += sh[k + 2] * w[(long)(k + 2) * 512];
        s3 += sh[k + 3] * w[(long)(k + 3) * 512];
    }
    wop[((long)kc * B_ + b) * 512 + o] = (s0 + s1) + (s2 + s3);
}

// ---------- reduce Wo partials -> out0 ----------
__global__ __launch_bounds__(256) void k_wored(const float* __restrict__ wop,
                                               float* __restrict__ out0) {
    int b = blockIdx.x, t = threadIdx.x;
    #pragma unroll
    for (int i = 0; i < 2; ++i) {
        int o = i * 256 + t;
        float s = 0.f;
        #pragma unroll
        for (int kc = 0; kc < 4; ++kc) s += wop[((long)kc * B_ + b) * 512 + o];
        out0[(long)b * 512 + o] = s;
    }
}

extern "C" void kernel_launch(void* const* d_in, const int* in_sizes, int n_in,
                              void* d_out, int out_size, void* d_ws, size_t ws_size,
                              hipStream_t stream) {
    const float* query = (const float*)d_in[0];
    const float* key   = (const float*)d_in[1];
    const float* Wq    = (const float*)d_in[2];
    const float* Wk    = (const float*)d_in[3];
    const float* Wv    = (const float*)d_in[4];
    const float* Wo    = (const float*)d_in[5];
    const float* lq1   = (const float*)d_in[6];
    const float* lk1   = (const float*)d_in[7];
    const float* lq2   = (const float*)d_in[8];
    const float* lk2   = (const float*)d_in[9];
    const float* rmsw  = (const float*)d_in[10];

    float* out0 = (float*)d_out;           // [64,1,512]
    float* out1 = out0 + B_ * E_;          // diff_attn [64,8,1,2048]

    // ws layout (floats): qkfrag(bf16, 262144 f) | wexp[64][16][2048] | apart[8][64][16][512] |
    //                     ms[8192] | zs[8192] | on[65536] | wop[131072]   (~44 MB, ws = 1 GiB)
    unsigned short* qkfrag = (unsigned short*)d_ws;
    float* wexp  = (float*)d_ws + 262144;
    float* apart = wexp + (long)B_ * 16 * P_;            // + 2097152
    float* ms    = apart + (long)NC_ * B_ * 16 * E_;     // + 4194304
    float* zs    = ms + NC_ * B_ * 16;
    float* on    = zs + NC_ * B_ * 16;
    float* wop   = on + B_ * D_;

    hipLaunchKernelGGL(k_qproj, dim3(4, B_),   dim3(256), 0, stream, query, Wq, Wk, qkfrag);
    hipLaunchKernelGGL(k_fused, dim3(NC_, B_), dim3(256), 0, stream, key, qkfrag, wexp, ms, zs, apart);
    hipLaunchKernelGGL(k_comb,  dim3(H_, B_),  dim3(256), 0, stream, wexp, ms, zs, apart,
                       lq1, lk1, lq2, lk2, Wv, rmsw, out1, on);
    hipLaunchKernelGGL(k_wo,    dim3(8, B_),   dim3(256), 0, stream, on, Wo, wop);
    hipLaunchKernelGGL(k_wored, dim3(B_),      dim3(256), 0, stream, wop, out0);
}